// Round 20
// baseline (418.035 us; speedup 1.0000x reference)
//
#include <hip/hip_runtime.h>
#include <math.h>

// ---------------------------------------------------------------------------
// SelfAttention (B=4, C=256, H=W=48, A=8, hid=512) on MI355X, bf16 MFMA.
// v16 = v15 + 32x32x16 MFMA in the S-phase of fused_attn (halves S-phase LDS
// key-fragment reads; Ps content unchanged, PV phase untouched).
//   S_z = (t@G_z + c_z) @ t^T,  G_z = Wq_z Wk_z^T;  VWo_z = t@M_z (+d_z)
//   out = diag(1/l) (exp(S) @ VWo) summed over heads + d + bo
// ---------------------------------------------------------------------------

typedef __bf16 bf16x8 __attribute__((ext_vector_type(8)));
typedef float f32x4 __attribute__((ext_vector_type(4)));
typedef float f32x16 __attribute__((ext_vector_type(16)));
typedef unsigned short ushort4v __attribute__((ext_vector_type(4)));

#define MFMA16(a, b, c) __builtin_amdgcn_mfma_f32_16x16x32_bf16(a, b, c, 0, 0, 0)
#define MFMA32(a, b, c) __builtin_amdgcn_mfma_f32_32x32x16_bf16(a, b, c, 0, 0, 0)

#define NTOK 2304
#define CIN 256
#define DTOT 4096
#define HID 512

__device__ __forceinline__ unsigned short f2bf(float f) {
  union { float f; unsigned int u; } v;
  v.f = f;
  unsigned int r = v.u + 0x7fffu + ((v.u >> 16) & 1u);  // RNE
  return (unsigned short)(r >> 16);
}
__device__ __forceinline__ float bf2f(unsigned short u) {
  union { unsigned int u; float f; } v;
  v.u = (unsigned int)u << 16;
  return v.f;
}

__device__ __forceinline__ void gload16(const void* g, void* l) {
  __builtin_amdgcn_global_load_lds(
      (const __attribute__((address_space(1))) unsigned int*)g,
      (__attribute__((address_space(3))) unsigned int*)l, 16, 0, 0);
}

__device__ __forceinline__ float rsum16(float v) {
  v += __shfl_xor(v, 1);
  v += __shfl_xor(v, 2);
  v += __shfl_xor(v, 4);
  v += __shfl_xor(v, 8);
  return v;
}
__device__ __forceinline__ float rsum32(float v) {
  v += __shfl_xor(v, 1);
  v += __shfl_xor(v, 2);
  v += __shfl_xor(v, 4);
  v += __shfl_xor(v, 8);
  v += __shfl_xor(v, 16);
  return v;
}

// ---------------------------------------------------------------------------
// Transpose fp32 (R x C) -> bf16 (C x R), batched over z (z-strided source).
// ---------------------------------------------------------------------------
__global__ void transpose_to_bf16(const float* __restrict__ src,
                                  unsigned short* __restrict__ dst,
                                  int R, int C, size_t szs, size_t dzs) {
  __shared__ float tile[32][33];
  src += (size_t)blockIdx.z * szs;
  unsigned short* d = dst + (size_t)blockIdx.z * dzs;
  int c0 = blockIdx.x * 32, r0 = blockIdx.y * 32;
  int tx = threadIdx.x, ty0 = threadIdx.y;
#pragma unroll
  for (int i = 0; i < 4; i++) {
    int ty = ty0 + i * 8;
    tile[ty][tx] = src[(size_t)(r0 + ty) * C + c0 + tx];
  }
  __syncthreads();
#pragma unroll
  for (int i = 0; i < 4; i++) {
    int ty = ty0 + i * 8;
    d[(size_t)(c0 + ty) * R + r0 + tx] = f2bf(tile[tx][ty]);
  }
}

// ---------------------------------------------------------------------------
// Elementwise f32 -> bf16 copy, 3 tensors of 1M elements (Wq, Wk, Wv).
// ---------------------------------------------------------------------------
__global__ void conv_bf16(const float* __restrict__ s0,
                          const float* __restrict__ s1,
                          const float* __restrict__ s2,
                          unsigned short* __restrict__ d0,
                          unsigned short* __restrict__ d1,
                          unsigned short* __restrict__ d2) {
  const float* s = blockIdx.y == 0 ? s0 : (blockIdx.y == 1 ? s1 : s2);
  unsigned short* d = blockIdx.y == 0 ? d0 : (blockIdx.y == 1 ? d1 : d2);
  size_t i = ((size_t)blockIdx.x * 256 + threadIdx.x) * 4;
#pragma unroll
  for (int j = 0; j < 4; j++) d[i + j] = f2bf(s[i + j]);
}

// ---------------------------------------------------------------------------
// H-GEMM: Out[z][m][n] = sum_e A[m][z*512+e] * B[n][z*512+e]  (bf16).
// grid (2, 2, 8), K=512.  Hmat (A=Wk_bf, B=Wq_bf); MmatT (A=WoT, B=Wv_bf).
// ---------------------------------------------------------------------------
__global__ __launch_bounds__(256, 3) void hgemm(
    const unsigned short* __restrict__ A_, const unsigned short* __restrict__ B_,
    unsigned short* __restrict__ Out_) {
  __shared__ __align__(16) char smem[36864];
  unsigned short* As = (unsigned short*)smem;
  unsigned short* Bs = As + 128 * 64;
  const int z = blockIdx.z;
  const int tid = threadIdx.x;
  const int w = tid >> 6, lane = tid & 63;
  const int wr = w >> 1, wc = w & 1;
  const int l15 = lane & 15, h = lane >> 4, l7 = lane & 7;
  const int mbase = blockIdx.x * 128, nbase = blockIdx.y * 128;
  f32x4 acc[4][4] = {};
  for (int kt = 0; kt < 8; kt++) {
#pragma unroll
    for (int is = 0; is < 4; is++) {
      int row = is * 32 + (tid >> 3);
      int cl = tid & 7;
      int gc = cl ^ (row & 7);
      gload16(A_ + (size_t)(mbase + row) * DTOT + z * 512 + kt * 64 + gc * 8,
              (char*)As + row * 128 + cl * 16);
      gload16(B_ + (size_t)(nbase + row) * DTOT + z * 512 + kt * 64 + gc * 8,
              (char*)Bs + row * 128 + cl * 16);
    }
    __syncthreads();
#pragma unroll
    for (int ks = 0; ks < 2; ks++) {
      bf16x8 a[4], b[4];
#pragma unroll
      for (int m = 0; m < 4; m++)
        a[m] = *(const bf16x8*)((char*)As + (wr * 64 + m * 16 + l15) * 128 +
                                (((ks * 4 + h) ^ l7) * 16));
#pragma unroll
      for (int n = 0; n < 4; n++)
        b[n] = *(const bf16x8*)((char*)Bs + (wc * 64 + n * 16 + l15) * 128 +
                                (((ks * 4 + h) ^ l7) * 16));
#pragma unroll
      for (int m = 0; m < 4; m++)
#pragma unroll
        for (int n = 0; n < 4; n++) acc[m][n] = MFMA16(a[m], b[n], acc[m][n]);
    }
    __syncthreads();
  }
  unsigned short* ldso = (unsigned short*)(smem + w * 9216);  // [64][72]
#pragma unroll
  for (int m = 0; m < 4; m++)
#pragma unroll
    for (int n = 0; n < 4; n++)
#pragma unroll
      for (int r = 0; r < 4; r++)
        ldso[(m * 16 + h * 4 + r) * 72 + n * 16 + l15] = f2bf(acc[m][n][r]);
  __syncthreads();
  unsigned short* Out = Out_ + (size_t)z * 65536;
#pragma unroll
  for (int pp = 0; pp < 8; pp++) {
    int q = pp * 8 + (lane >> 3);
    int ec = (lane & 7) * 8;
    *(bf16x8*)(Out + (size_t)(mbase + wr * 64 + q) * 256 + nbase + wc * 64 +
               ec) = *(const bf16x8*)(ldso + q * 72 + ec);
  }
}

// ---------------------------------------------------------------------------
// cvec[z][c'] = sum_e bq[z*512+e] * Wk[c'][z*512+e]  (f32).  grid 8 x 256.
// ---------------------------------------------------------------------------
__global__ void cvec_kernel(const float* __restrict__ Wk,
                            const float* __restrict__ bq,
                            float* __restrict__ cvec) {
  int z = blockIdx.x, c = threadIdx.x;
  float s = 0.f;
  const float* wr_ = Wk + (size_t)c * DTOT + z * 512;
  const float* br = bq + z * 512;
  for (int e = 0; e < 512; e++) s += br[e] * wr_[e];
  cvec[z * 256 + c] = s;
}

// ---------------------------------------------------------------------------
// dvec[z][c] = sum_e bv[z*512+e] * Wo[(z*512+e)][c]  (f32).  grid 8 x 256.
// ---------------------------------------------------------------------------
__global__ void dvec_kernel(const float* __restrict__ Wo,
                            const float* __restrict__ bv,
                            float* __restrict__ dvec) {
  int z = blockIdx.x, c = threadIdx.x;
  float s = 0.f;
  const float* br = bv + z * 512;
  const float* wr_ = Wo + (size_t)z * 512 * CIN + c;
  for (int e = 0; e < 512; e++) s += br[e] * wr_[(size_t)e * CIN];
  dvec[z * 256 + c] = s;
}

// ---------------------------------------------------------------------------
// proj2: combined U / VWoT projections (K=256), batched.  grid (18, 32, 4):
//   y<16:  U[((b*8+z)*2304+tok)*256+col] = t_b@Hmat_z + cvec_z   (z = y/2)
//   y>=16: VWoT[((b*8+z)*256+col)*2304+tok] = t_b@MmatT_z        (z=(y-16)/2)
// ---------------------------------------------------------------------------
__global__ __launch_bounds__(256, 3) void proj2(
    const unsigned short* __restrict__ Tb, const unsigned short* __restrict__ H,
    const float* __restrict__ cvec, const unsigned short* __restrict__ M,
    unsigned short* __restrict__ Uo, unsigned short* __restrict__ VWo) {
  __shared__ __align__(16) char smem[36864];
  unsigned short* As = (unsigned short*)smem;
  unsigned short* Bs = As + 128 * 64;
  const int bb = blockIdx.z;
  const unsigned short* T = Tb + (size_t)bb * NTOK * CIN;
  int y = blockIdx.y;
  const unsigned short* B;
  const float* bias;
  unsigned short* Out;
  int layout;
  if (y < 16) {
    B = H; bias = cvec; Out = Uo; layout = 0;
  } else {
    B = M; bias = nullptr; Out = VWo; layout = 1; y -= 16;
  }
  const int tid = threadIdx.x;
  const int w = tid >> 6, lane = tid & 63;
  const int wr = w >> 1, wc = w & 1;
  const int l15 = lane & 15, h = lane >> 4, l7 = lane & 7;
  const int mbase = blockIdx.x * 128, nglob = y * 128;
  f32x4 acc[4][4] = {};
  for (int kt = 0; kt < 4; kt++) {
#pragma unroll
    for (int is = 0; is < 4; is++) {
      int row = is * 32 + (tid >> 3);
      int cl = tid & 7;
      int gc = cl ^ (row & 7);
      gload16(T + (size_t)(mbase + row) * CIN + kt * 64 + gc * 8,
              (char*)As + row * 128 + cl * 16);
      gload16(B + (size_t)(nglob + row) * 256 + kt * 64 + gc * 8,
              (char*)Bs + row * 128 + cl * 16);
    }
    __syncthreads();
#pragma unroll
    for (int ks = 0; ks < 2; ks++) {
      bf16x8 a[4], b[4];
#pragma unroll
      for (int m = 0; m < 4; m++)
        a[m] = *(const bf16x8*)((char*)As + (wr * 64 + m * 16 + l15) * 128 +
                                (((ks * 4 + h) ^ l7) * 16));
#pragma unroll
      for (int n = 0; n < 4; n++)
        b[n] = *(const bf16x8*)((char*)Bs + (wc * 64 + n * 16 + l15) * 128 +
                                (((ks * 4 + h) ^ l7) * 16));
#pragma unroll
      for (int m = 0; m < 4; m++)
#pragma unroll
        for (int n = 0; n < 4; n++) acc[m][n] = MFMA16(a[m], b[n], acc[m][n]);
    }
    __syncthreads();
  }
  float bias_n[4];
#pragma unroll
  for (int n = 0; n < 4; n++)
    bias_n[n] = bias ? bias[nglob + wc * 64 + n * 16 + l15] : 0.f;
  unsigned short* ldso = (unsigned short*)(smem + w * 9216);  // [64][72]
  const int ntok0 = mbase + wr * 64;
  const int z = nglob >> 8;
  const int col0 = (nglob & 255) + wc * 64;
  if (layout == 0) {
#pragma unroll
    for (int m = 0; m < 4; m++)
#pragma unroll
      for (int n = 0; n < 4; n++)
#pragma unroll
        for (int r = 0; r < 4; r++)
          ldso[(m * 16 + h * 4 + r) * 72 + n * 16 + l15] =
              f2bf(acc[m][n][r] + bias_n[n]);
    __syncthreads();
#pragma unroll
    for (int pp = 0; pp < 8; pp++) {
      int q = pp * 8 + (lane >> 3);
      int ec = (lane & 7) * 8;
      *(bf16x8*)(Out + (((size_t)bb * 8 + z) * NTOK + ntok0 + q) * 256 + col0 +
                 ec) = *(const bf16x8*)(ldso + q * 72 + ec);
    }
  } else {
#pragma unroll
    for (int m = 0; m < 4; m++)
#pragma unroll
      for (int n = 0; n < 4; n++)
#pragma unroll
        for (int r = 0; r < 4; r++)
          ldso[(n * 16 + l15) * 72 + m * 16 + h * 4 + r] =
              f2bf(acc[m][n][r] + bias_n[n]);
    __syncthreads();
#pragma unroll
    for (int pp = 0; pp < 8; pp++) {
      int cc = pp * 8 + (lane >> 3);
      int tc = (lane & 7) * 8;
      *(bf16x8*)(Out + (((size_t)bb * 8 + z) * 256 + col0 + cc) * NTOK +
                 ntok0 + tc) = *(const bf16x8*)(ldso + cc * 72 + tc);
    }
  }
}

// ---------------------------------------------------------------------------
// fused_attn (v15 + 32x32 S-phase): per block (b, 64 q, head z, key-half s):
// 18 chunks of 64 keys, 2 barriers/chunk with T14 async staging.
// S: 4 waves each compute one 32x32 tile (qh=w>>1, kh=w&1) with MFMA32 over
// K=256 (16 steps) -> exp -> Ps [q][k] (same layout as before) -> PV with
// MFMA16 (unchanged).  O bf16, l f32 per (s,kh) slot.
// grid 2304: i = ((b*36+qt)*2+s)*8+z.  LDS: Ts 32K | Ws 32K | Ps 8K.
// ---------------------------------------------------------------------------
__global__ __launch_bounds__(256, 2) void fused_attn(
    const unsigned short* __restrict__ Ub, const unsigned short* __restrict__ Tb,
    const unsigned short* __restrict__ VWoT, unsigned short* __restrict__ Opart,
    float* __restrict__ l_part) {
  __shared__ __align__(16) char smem[73728];
  unsigned short* Ts = (unsigned short*)smem;            // [64][256]
  unsigned short* Ws = (unsigned short*)(smem + 32768);  // [256][64]
  unsigned short* Ps = (unsigned short*)(smem + 65536);  // [64][64]
  const int i = blockIdx.x;
  const int z = i & 7;
  const int s = (i >> 3) & 1;
  const int qt = (i >> 4) % 36;
  const int bb = (i >> 4) / 36;
  const int q0 = qt * 64;
  const int k0 = s * 1152;
  const int tid = threadIdx.x;
  const int w = tid >> 6, lane = tid & 63;
  const int l15 = lane & 15, h = lane >> 4;
  const int l31 = lane & 31, hi = lane >> 5;
  const int qh = w >> 1, kh = w & 1;

  const unsigned short* U = Ub + ((size_t)bb * 8 + z) * NTOK * 256;
  const unsigned short* T = Tb + (size_t)bb * NTOK * CIN;
  const unsigned short* Wv = VWoT + ((size_t)bb * 8 + z) * 256 * NTOK;

  // prologue: stage U tile into Ts region, pull 32x32 A-fragments into regs
#pragma unroll
  for (int it = 0; it < 8; it++) {
    int f = it * 256 + tid;
    int row = f >> 5, cb = f & 31;
    gload16(U + (size_t)(q0 + row) * 256 + (size_t)((cb ^ (row & 7)) * 8),
            (char*)smem + (size_t)f * 16);
  }
  __syncthreads();
  bf16x8 ua[16];
  {
    int row = qh * 32 + l31;  // A: row = lane&31, k-base = (lane>>5)*8
#pragma unroll
    for (int ks = 0; ks < 16; ks++)
      ua[ks] = *(const bf16x8*)((char*)Ts + row * 512 +
                                (((ks * 2 + hi) ^ (row & 7)) * 16));
  }
  f32x4 oacc[4][4] = {};
  float lacc[16];
#pragma unroll
  for (int r = 0; r < 16; r++) lacc[r] = 0.f;
  __syncthreads();  // all waves done reading U from Ts

  // pre-stage chunk 0 (t + VWo)
#pragma unroll
  for (int it = 0; it < 8; it++) {
    int f = it * 256 + tid;
    int row = f >> 5, cb = f & 31;
    gload16(T + (size_t)(k0 + row) * 256 + (size_t)((cb ^ (row & 7)) * 8),
            (char*)smem + (size_t)f * 16);
  }
#pragma unroll
  for (int it = 0; it < 8; it++) {
    int row = it * 32 + (tid >> 3);
    int cl = tid & 7, gc = cl ^ (row & 7);
    gload16(Wv + (size_t)row * NTOK + k0 + gc * 8,
            (char*)Ws + row * 128 + cl * 16);
  }
  __syncthreads();  // chunk 0 staged

  for (int kt = 0; kt < 18; kt++) {
    // S = U @ t^T : wave computes 32x32 tile (qh, kh) over K=256
    f32x16 sacc = {};
    const int key = kh * 32 + l31;  // B: col = lane&31, k-base = (lane>>5)*8
    __builtin_amdgcn_s_setprio(1);
#pragma unroll
    for (int ks = 0; ks < 16; ks++) {
      bf16x8 tb_ = *(const bf16x8*)((char*)Ts + key * 512 +
                                    (((ks * 2 + hi) ^ (key & 7)) * 16));
      sacc = MFMA32(ua[ks], tb_, sacc);
    }
    __builtin_amdgcn_s_setprio(0);
    // P = exp(S) -> Ps (same [q][k] swizzled layout), l accumulate
#pragma unroll
    for (int r = 0; r < 16; r++) {
      float pv = __expf(sacc[r]);
      lacc[r] += pv;
      int q = qh * 32 + (r & 3) + 8 * (r >> 2) + 4 * hi;  // C/D row map
      int k = key;
      Ps[q * 64 + (((k >> 3) ^ (q & 7)) << 3) + (k & 7)] = f2bf(pv);
    }
    __syncthreads();  // B1: Ps visible; Ts free; drains Ws_{kt} stage
    // issue t-stage for next chunk (hides under PV; drained at B2)
    if (kt + 1 < 18) {
      const int kb = k0 + (kt + 1) * 64;
#pragma unroll
      for (int it = 0; it < 8; it++) {
        int f = it * 256 + tid;
        int row = f >> 5, cb = f & 31;
        gload16(T + (size_t)(kb + row) * 256 + (size_t)((cb ^ (row & 7)) * 8),
                (char*)smem + (size_t)f * 16);
      }
    }
    // O += P @ VWo : wave w owns c-slice w*64..+63, all 64 q (MFMA16)
    __builtin_amdgcn_s_setprio(1);
#pragma unroll
    for (int ks2 = 0; ks2 < 2; ks2++) {
      bf16x8 pa[4];
#pragma unroll
      for (int m = 0; m < 4; m++) {
        int q = m * 16 + l15;
        pa[m] = *(const bf16x8*)((char*)Ps + q * 128 +
                                 (((ks2 * 4 + h) ^ (q & 7)) * 16));
      }
#pragma unroll
      for (int n = 0; n < 4; n++) {
        int c = w * 64 + n * 16 + l15;
        bf16x8 wb = *(const bf16x8*)((char*)Ws + c * 128 +
                                     (((ks2 * 4 + h) ^ (c & 7)) * 16));
#pragma unroll
        for (int m = 0; m < 4; m++) oacc[m][n] = MFMA16(pa[m], wb, oacc[m][n]);
      }
    }
    __builtin_amdgcn_s_setprio(0);
    __syncthreads();  // B2: PV done; Ws free; drains t_{kt+1} stage
    // issue Ws-stage for next chunk (hides under next S; drained at B1)
    if (kt + 1 < 18) {
      const int kb = k0 + (kt + 1) * 64;
#pragma unroll
      for (int it = 0; it < 8; it++) {
        int row = it * 32 + (tid >> 3);
        int cl = tid & 7, gc = cl ^ (row & 7);
        gload16(Wv + (size_t)row * NTOK + kb + gc * 8,
                (char*)Ws + row * 128 + cl * 16);
      }
    }
  }
  // l: reduce each row over the 32 key-lanes; lanes l31==0 write 16 rows.
  // slot (s, kh): summed with the other slots in reduce_out2.
  {
    float* lp = l_part +
        ((((size_t)bb * 2 + s) * 8 + z) * 2 + kh) * NTOK + q0 + qh * 32;
#pragma unroll
    for (int r = 0; r < 16; r++) {
      float v = rsum32(lacc[r]);
      if (l31 == 0) lp[(r & 3) + 8 * (r >> 2) + 4 * hi] = v;
    }
  }
  // O epilogue: per-wave LDS transpose [64 c][72 q] bf16, coalesced store
  unsigned short* ldso = (unsigned short*)(smem + w * 9216);
#pragma unroll
  for (int m = 0; m < 4; m++)
#pragma unroll
    for (int n = 0; n < 4; n++)
#pragma unroll
      for (int r = 0; r < 4; r++)
        ldso[(n * 16 + l15) * 72 + m * 16 + h * 4 + r] = f2bf(oacc[m][n][r]);
  unsigned short* Out =
      Opart + ((((size_t)bb * 2 + s) * 8 + z) * 256 + w * 64) * NTOK + q0;
#pragma unroll
  for (int pp = 0; pp < 8; pp++) {
    int cc = pp * 8 + (lane >> 3);
    int qc = (lane & 7) * 8;
    *(bf16x8*)(Out + (size_t)cc * NTOK + qc) =
        *(const bf16x8*)(ldso + cc * 72 + qc);
  }
}

// ---------------------------------------------------------------------------
// reduce_out2: out[b][c][q] = bo[c] + sum_z [ (O0+O1)/(sum of 4 l slots) + d ].
// grid (576, 4).  Opart bf16 [b][s][z][c][q];  l_part f32 [b][s][z][kh][q].
// ---------------------------------------------------------------------------
__global__ void reduce_out2(const unsigned short* __restrict__ Opart,
                            const float* __restrict__ l_part,
                            const float* __restrict__ dvec,
                            const float* __restrict__ bo,
                            float* __restrict__ out) {
  const int bb = blockIdx.y;
  int idx = (blockIdx.x * 256 + threadIdx.x) * 4;  // [0, 256*2304)
  int c = idx / NTOK;
  int q = idx - c * NTOK;
  const unsigned short* Ob = Opart + (size_t)bb * 2 * 8 * 256 * NTOK;
  const float* lb = l_part + (size_t)bb * 2 * 8 * 2 * NTOK;
  f32x4 acc = {bo[c], bo[c], bo[c], bo[c]};
#pragma unroll
  for (int z = 0; z < 8; z++) {
    ushort4v o0 = *(const ushort4v*)&Ob[((size_t)z * 256 + c) * NTOK + q];
    ushort4v o1 = *(const ushort4v*)&Ob[((size_t)(8 + z) * 256 + c) * NTOK + q];
    f32x4 l00 = *(const f32x4*)&lb[((size_t)z * 2 + 0) * NTOK + q];
    f32x4 l01 = *(const f32x4*)&lb[((size_t)z * 2 + 1) * NTOK + q];
    f32x4 l10 = *(const f32x4*)&lb[((size_t)(8 + z) * 2 + 0) * NTOK + q];
    f32x4 l11 = *(const f32x4*)&lb[((size_t)(8 + z) * 2 + 1) * NTOK + q];
    float d = dvec[z * 256 + c];
#pragma unroll
    for (int j = 0; j < 4; j++)
      acc[j] += (bf2f(o0[j]) + bf2f(o1[j])) /
                    (l00[j] + l01[j] + l10[j] + l11[j]) + d;
  }
  *(f32x4*)&out[(size_t)bb * CIN * NTOK + idx] = acc;
}

// ---------------------------------------------------------------------------
extern "C" void kernel_launch(void* const* d_in, const int* in_sizes, int n_in,
                              void* d_out, int out_size, void* d_ws,
                              size_t ws_size, hipStream_t stream) {
  const float* x = (const float*)d_in[0];
  const float* Wq = (const float*)d_in[1];
  const float* bq = (const float*)d_in[2];
  const float* Wk = (const float*)d_in[3];
  const float* bk = (const float*)d_in[4];
  const float* Wv = (const float*)d_in[5];
  const float* bv = (const float*)d_in[6];
  const float* Wo = (const float*)d_in[7];
  const float* bo = (const float*)d_in[8];
  float* out = (float*)d_out;
  (void)bk;  // bk terms are per-row softmax constants -> cancel exactly

  // ---- workspace layout (bf16 elements); total ~167 MB
  unsigned short* Wq_bf = (unsigned short*)d_ws;      // 256 x 4096
  unsigned short* Wk_bf = Wq_bf + 1048576;
  unsigned short* Wv_bf = Wk_bf + 1048576;
  unsigned short* WoT = Wv_bf + 1048576;              // 256 x 4096
  unsigned short* Hmat = WoT + 1048576;               // [8][256][256]
  unsigned short* MmatT = Hmat + 524288;              // [8][256][256]
  float* cvec = (float*)(MmatT + 524288);             // [8][256]
  float* dvec = cvec + 2048;                          // [8][256]
  unsigned short* tb = (unsigned short*)(dvec + 2048);  // [4][2304][256]
  unsigned short* Uc = tb + 4ull * 589824;            // [4][8][2304][256]
  unsigned short* VWoT = Uc + 32ull * 589824;         // [4][8][256][2304]
  unsigned short* Opart = VWoT + 32ull * 589824;      // [4][2][8][256][2304]
  float* l_part = (float*)(Opart + 64ull * 589824);   // [4][2][8][2][2304] f32
  size_t need_el = (size_t)((unsigned short*)(l_part + 4 * 2 * 8 * 2 * NTOK) -
                            (unsigned short*)d_ws);
  if (ws_size / 2 < need_el) return;

  dim3 tp(32, 8);
  conv_bf16<<<dim3(1024, 3), 256, 0, stream>>>(Wq, Wk, Wv, Wq_bf, Wk_bf,
                                               Wv_bf);
  transpose_to_bf16<<<dim3(72, 8, 4), tp, 0, stream>>>(
      x, tb, CIN, NTOK, (size_t)CIN * NTOK, (size_t)NTOK * CIN);
  transpose_to_bf16<<<dim3(8, 128, 1), tp, 0, stream>>>(Wo, WoT, DTOT, CIN, 0,
                                                        0);
  hgemm<<<dim3(2, 2, 8), 256, 0, stream>>>(Wk_bf, Wq_bf, Hmat);
  hgemm<<<dim3(2, 2, 8), 256, 0, stream>>>(WoT, Wv_bf, MmatT);
  cvec_kernel<<<dim3(8), 256, 0, stream>>>(Wk, bq, cvec);
  dvec_kernel<<<dim3(8), 256, 0, stream>>>(Wo, bv, dvec);

  proj2<<<dim3(18, 32, 4), 256, 0, stream>>>(tb, Hmat, cvec, MmatT, Uc, VWoT);
  fused_attn<<<dim3(2304), 256, 0, stream>>>(Uc, tb, VWoT, Opart, l_part);
  reduce_out2<<<dim3(576, 4), 256, 0, stream>>>(Opart, l_part, dvec, bo, out);
}

// Round 21
// 328.478 us; speedup vs baseline: 1.2726x; 1.2726x over previous
//
#include <hip/hip_runtime.h>
#include <math.h>

// ---------------------------------------------------------------------------
// SelfAttention (B=4, C=256, H=W=48, A=8, hid=512) on MI355X, bf16 MFMA.
// v17 == v15 (round-19 champion, 332 us): rank-256 compression + fused
// attention with T14 async staging (2 barriers/chunk).
//   S_z = (t@G_z + c_z) @ t^T,  G_z = Wq_z Wk_z^T;  VWo_z = t@M_z (+d_z)
//   out = diag(1/l) (exp(S) @ VWo) summed over heads + d + bo
// v16 (32x32 S-phase) regressed: VGPR 128 ceiling -> spill (WRITE 74->111MB),
// serial 16-chain MFMA32 killed ILP.  This design family's optimum is v15.
// ---------------------------------------------------------------------------

typedef __bf16 bf16x8 __attribute__((ext_vector_type(8)));
typedef float f32x4 __attribute__((ext_vector_type(4)));
typedef unsigned short ushort4v __attribute__((ext_vector_type(4)));

#define MFMA16(a, b, c) __builtin_amdgcn_mfma_f32_16x16x32_bf16(a, b, c, 0, 0, 0)

#define NTOK 2304
#define CIN 256
#define DTOT 4096
#define HID 512

__device__ __forceinline__ unsigned short f2bf(float f) {
  union { float f; unsigned int u; } v;
  v.f = f;
  unsigned int r = v.u + 0x7fffu + ((v.u >> 16) & 1u);  // RNE
  return (unsigned short)(r >> 16);
}
__device__ __forceinline__ float bf2f(unsigned short u) {
  union { unsigned int u; float f; } v;
  v.u = (unsigned int)u << 16;
  return v.f;
}

__device__ __forceinline__ void gload16(const void* g, void* l) {
  __builtin_amdgcn_global_load_lds(
      (const __attribute__((address_space(1))) unsigned int*)g,
      (__attribute__((address_space(3))) unsigned int*)l, 16, 0, 0);
}

__device__ __forceinline__ float rsum16(float v) {
  v += __shfl_xor(v, 1);
  v += __shfl_xor(v, 2);
  v += __shfl_xor(v, 4);
  v += __shfl_xor(v, 8);
  return v;
}

// ---------------------------------------------------------------------------
// Transpose fp32 (R x C) -> bf16 (C x R), batched over z (z-strided source).
// ---------------------------------------------------------------------------
__global__ void transpose_to_bf16(const float* __restrict__ src,
                                  unsigned short* __restrict__ dst,
                                  int R, int C, size_t szs, size_t dzs) {
  __shared__ float tile[32][33];
  src += (size_t)blockIdx.z * szs;
  unsigned short* d = dst + (size_t)blockIdx.z * dzs;
  int c0 = blockIdx.x * 32, r0 = blockIdx.y * 32;
  int tx = threadIdx.x, ty0 = threadIdx.y;
#pragma unroll
  for (int i = 0; i < 4; i++) {
    int ty = ty0 + i * 8;
    tile[ty][tx] = src[(size_t)(r0 + ty) * C + c0 + tx];
  }
  __syncthreads();
#pragma unroll
  for (int i = 0; i < 4; i++) {
    int ty = ty0 + i * 8;
    d[(size_t)(c0 + ty) * R + r0 + tx] = f2bf(tile[tx][ty]);
  }
}

// ---------------------------------------------------------------------------
// Elementwise f32 -> bf16 copy, 3 tensors of 1M elements (Wq, Wk, Wv).
// ---------------------------------------------------------------------------
__global__ void conv_bf16(const float* __restrict__ s0,
                          const float* __restrict__ s1,
                          const float* __restrict__ s2,
                          unsigned short* __restrict__ d0,
                          unsigned short* __restrict__ d1,
                          unsigned short* __restrict__ d2) {
  const float* s = blockIdx.y == 0 ? s0 : (blockIdx.y == 1 ? s1 : s2);
  unsigned short* d = blockIdx.y == 0 ? d0 : (blockIdx.y == 1 ? d1 : d2);
  size_t i = ((size_t)blockIdx.x * 256 + threadIdx.x) * 4;
#pragma unroll
  for (int j = 0; j < 4; j++) d[i + j] = f2bf(s[i + j]);
}

// ---------------------------------------------------------------------------
// H-GEMM: Out[z][m][n] = sum_e A[m][z*512+e] * B[n][z*512+e]  (bf16).
// grid (2, 2, 8), K=512.  Hmat (A=Wk_bf, B=Wq_bf); MmatT (A=WoT, B=Wv_bf).
// ---------------------------------------------------------------------------
__global__ __launch_bounds__(256, 3) void hgemm(
    const unsigned short* __restrict__ A_, const unsigned short* __restrict__ B_,
    unsigned short* __restrict__ Out_) {
  __shared__ __align__(16) char smem[36864];
  unsigned short* As = (unsigned short*)smem;
  unsigned short* Bs = As + 128 * 64;
  const int z = blockIdx.z;
  const int tid = threadIdx.x;
  const int w = tid >> 6, lane = tid & 63;
  const int wr = w >> 1, wc = w & 1;
  const int l15 = lane & 15, h = lane >> 4, l7 = lane & 7;
  const int mbase = blockIdx.x * 128, nbase = blockIdx.y * 128;
  f32x4 acc[4][4] = {};
  for (int kt = 0; kt < 8; kt++) {
#pragma unroll
    for (int is = 0; is < 4; is++) {
      int row = is * 32 + (tid >> 3);
      int cl = tid & 7;
      int gc = cl ^ (row & 7);
      gload16(A_ + (size_t)(mbase + row) * DTOT + z * 512 + kt * 64 + gc * 8,
              (char*)As + row * 128 + cl * 16);
      gload16(B_ + (size_t)(nbase + row) * DTOT + z * 512 + kt * 64 + gc * 8,
              (char*)Bs + row * 128 + cl * 16);
    }
    __syncthreads();
#pragma unroll
    for (int ks = 0; ks < 2; ks++) {
      bf16x8 a[4], b[4];
#pragma unroll
      for (int m = 0; m < 4; m++)
        a[m] = *(const bf16x8*)((char*)As + (wr * 64 + m * 16 + l15) * 128 +
                                (((ks * 4 + h) ^ l7) * 16));
#pragma unroll
      for (int n = 0; n < 4; n++)
        b[n] = *(const bf16x8*)((char*)Bs + (wc * 64 + n * 16 + l15) * 128 +
                                (((ks * 4 + h) ^ l7) * 16));
#pragma unroll
      for (int m = 0; m < 4; m++)
#pragma unroll
        for (int n = 0; n < 4; n++) acc[m][n] = MFMA16(a[m], b[n], acc[m][n]);
    }
    __syncthreads();
  }
  unsigned short* ldso = (unsigned short*)(smem + w * 9216);  // [64][72]
#pragma unroll
  for (int m = 0; m < 4; m++)
#pragma unroll
    for (int n = 0; n < 4; n++)
#pragma unroll
      for (int r = 0; r < 4; r++)
        ldso[(m * 16 + h * 4 + r) * 72 + n * 16 + l15] = f2bf(acc[m][n][r]);
  __syncthreads();
  unsigned short* Out = Out_ + (size_t)z * 65536;
#pragma unroll
  for (int pp = 0; pp < 8; pp++) {
    int q = pp * 8 + (lane >> 3);
    int ec = (lane & 7) * 8;
    *(bf16x8*)(Out + (size_t)(mbase + wr * 64 + q) * 256 + nbase + wc * 64 +
               ec) = *(const bf16x8*)(ldso + q * 72 + ec);
  }
}

// ---------------------------------------------------------------------------
// cvec[z][c'] = sum_e bq[z*512+e] * Wk[c'][z*512+e]  (f32).  grid 8 x 256.
// ---------------------------------------------------------------------------
__global__ void cvec_kernel(const float* __restrict__ Wk,
                            const float* __restrict__ bq,
                            float* __restrict__ cvec) {
  int z = blockIdx.x, c = threadIdx.x;
  float s = 0.f;
  const float* wr_ = Wk + (size_t)c * DTOT + z * 512;
  const float* br = bq + z * 512;
  for (int e = 0; e < 512; e++) s += br[e] * wr_[e];
  cvec[z * 256 + c] = s;
}

// ---------------------------------------------------------------------------
// dvec[z][c] = sum_e bv[z*512+e] * Wo[(z*512+e)][c]  (f32).  grid 8 x 256.
// ---------------------------------------------------------------------------
__global__ void dvec_kernel(const float* __restrict__ Wo,
                            const float* __restrict__ bv,
                            float* __restrict__ dvec) {
  int z = blockIdx.x, c = threadIdx.x;
  float s = 0.f;
  const float* br = bv + z * 512;
  const float* wr_ = Wo + (size_t)z * 512 * CIN + c;
  for (int e = 0; e < 512; e++) s += br[e] * wr_[(size_t)e * CIN];
  dvec[z * 256 + c] = s;
}

// ---------------------------------------------------------------------------
// proj2: combined U / VWoT projections (K=256), batched.  grid (18, 32, 4):
//   y<16:  U[((b*8+z)*2304+tok)*256+col] = t_b@Hmat_z + cvec_z   (z = y/2)
//   y>=16: VWoT[((b*8+z)*256+col)*2304+tok] = t_b@MmatT_z        (z=(y-16)/2)
// ---------------------------------------------------------------------------
__global__ __launch_bounds__(256, 3) void proj2(
    const unsigned short* __restrict__ Tb, const unsigned short* __restrict__ H,
    const float* __restrict__ cvec, const unsigned short* __restrict__ M,
    unsigned short* __restrict__ Uo, unsigned short* __restrict__ VWo) {
  __shared__ __align__(16) char smem[36864];
  unsigned short* As = (unsigned short*)smem;
  unsigned short* Bs = As + 128 * 64;
  const int bb = blockIdx.z;
  const unsigned short* T = Tb + (size_t)bb * NTOK * CIN;
  int y = blockIdx.y;
  const unsigned short* B;
  const float* bias;
  unsigned short* Out;
  int layout;
  if (y < 16) {
    B = H; bias = cvec; Out = Uo; layout = 0;
  } else {
    B = M; bias = nullptr; Out = VWo; layout = 1; y -= 16;
  }
  const int tid = threadIdx.x;
  const int w = tid >> 6, lane = tid & 63;
  const int wr = w >> 1, wc = w & 1;
  const int l15 = lane & 15, h = lane >> 4, l7 = lane & 7;
  const int mbase = blockIdx.x * 128, nglob = y * 128;
  f32x4 acc[4][4] = {};
  for (int kt = 0; kt < 4; kt++) {
#pragma unroll
    for (int is = 0; is < 4; is++) {
      int row = is * 32 + (tid >> 3);
      int cl = tid & 7;
      int gc = cl ^ (row & 7);
      gload16(T + (size_t)(mbase + row) * CIN + kt * 64 + gc * 8,
              (char*)As + row * 128 + cl * 16);
      gload16(B + (size_t)(nglob + row) * 256 + kt * 64 + gc * 8,
              (char*)Bs + row * 128 + cl * 16);
    }
    __syncthreads();
#pragma unroll
    for (int ks = 0; ks < 2; ks++) {
      bf16x8 a[4], b[4];
#pragma unroll
      for (int m = 0; m < 4; m++)
        a[m] = *(const bf16x8*)((char*)As + (wr * 64 + m * 16 + l15) * 128 +
                                (((ks * 4 + h) ^ l7) * 16));
#pragma unroll
      for (int n = 0; n < 4; n++)
        b[n] = *(const bf16x8*)((char*)Bs + (wc * 64 + n * 16 + l15) * 128 +
                                (((ks * 4 + h) ^ l7) * 16));
#pragma unroll
      for (int m = 0; m < 4; m++)
#pragma unroll
        for (int n = 0; n < 4; n++) acc[m][n] = MFMA16(a[m], b[n], acc[m][n]);
    }
    __syncthreads();
  }
  float bias_n[4];
#pragma unroll
  for (int n = 0; n < 4; n++)
    bias_n[n] = bias ? bias[nglob + wc * 64 + n * 16 + l15] : 0.f;
  unsigned short* ldso = (unsigned short*)(smem + w * 9216);  // [64][72]
  const int ntok0 = mbase + wr * 64;
  const int z = nglob >> 8;
  const int col0 = (nglob & 255) + wc * 64;
  if (layout == 0) {
#pragma unroll
    for (int m = 0; m < 4; m++)
#pragma unroll
      for (int n = 0; n < 4; n++)
#pragma unroll
        for (int r = 0; r < 4; r++)
          ldso[(m * 16 + h * 4 + r) * 72 + n * 16 + l15] =
              f2bf(acc[m][n][r] + bias_n[n]);
    __syncthreads();
#pragma unroll
    for (int pp = 0; pp < 8; pp++) {
      int q = pp * 8 + (lane >> 3);
      int ec = (lane & 7) * 8;
      *(bf16x8*)(Out + (((size_t)bb * 8 + z) * NTOK + ntok0 + q) * 256 + col0 +
                 ec) = *(const bf16x8*)(ldso + q * 72 + ec);
    }
  } else {
#pragma unroll
    for (int m = 0; m < 4; m++)
#pragma unroll
      for (int n = 0; n < 4; n++)
#pragma unroll
        for (int r = 0; r < 4; r++)
          ldso[(n * 16 + l15) * 72 + m * 16 + h * 4 + r] =
              f2bf(acc[m][n][r] + bias_n[n]);
    __syncthreads();
#pragma unroll
    for (int pp = 0; pp < 8; pp++) {
      int cc = pp * 8 + (lane >> 3);
      int tc = (lane & 7) * 8;
      *(bf16x8*)(Out + (((size_t)bb * 8 + z) * 256 + col0 + cc) * NTOK +
                 ntok0 + tc) = *(const bf16x8*)(ldso + cc * 72 + tc);
    }
  }
}

// ---------------------------------------------------------------------------
// fused_attn (v11 geometry + T14 async-stage): per block (batch b, 64 q rows,
// head z, key-half s): 18 chunks of 64 keys.  2 barriers/chunk:
//   S_k -> exp/Ps -> B1 -> issue t_{k+1} -> PV_k -> B2 -> issue Ws_{k+1}
// t-stage hides under PV, Ws-stage hides under S.  O bf16, l f32.
// grid 2304: i = ((b*36+qt)*2+s)*8+z.  LDS: Ts 32K | Ws 32K | Ps 8K.
// ---------------------------------------------------------------------------
__global__ __launch_bounds__(256, 2) void fused_attn(
    const unsigned short* __restrict__ Ub, const unsigned short* __restrict__ Tb,
    const unsigned short* __restrict__ VWoT, unsigned short* __restrict__ Opart,
    float* __restrict__ l_part) {
  __shared__ __align__(16) char smem[73728];
  unsigned short* Ts = (unsigned short*)smem;            // [64][256]
  unsigned short* Ws = (unsigned short*)(smem + 32768);  // [256][64]
  unsigned short* Ps = (unsigned short*)(smem + 65536);  // [64][64]
  const int i = blockIdx.x;
  const int z = i & 7;
  const int s = (i >> 3) & 1;
  const int qt = (i >> 4) % 36;
  const int bb = (i >> 4) / 36;
  const int q0 = qt * 64;
  const int k0 = s * 1152;
  const int tid = threadIdx.x;
  const int w = tid >> 6, lane = tid & 63;
  const int l15 = lane & 15, h = lane >> 4;

  const unsigned short* U = Ub + ((size_t)bb * 8 + z) * NTOK * 256;
  const unsigned short* T = Tb + (size_t)bb * NTOK * CIN;
  const unsigned short* Wv = VWoT + ((size_t)bb * 8 + z) * 256 * NTOK;

  // prologue: stage U tile into Ts region, pull A-fragments into registers
#pragma unroll
  for (int it = 0; it < 8; it++) {
    int f = it * 256 + tid;
    int row = f >> 5, cb = f & 31;
    gload16(U + (size_t)(q0 + row) * 256 + (size_t)((cb ^ (row & 7)) * 8),
            (char*)smem + (size_t)f * 16);
  }
  __syncthreads();
  bf16x8 ua[8];
  {
    int q = w * 16 + l15;
#pragma unroll
    for (int ks = 0; ks < 8; ks++)
      ua[ks] = *(const bf16x8*)((char*)Ts + q * 512 +
                                (((ks * 4 + h) ^ (q & 7)) * 16));
  }
  f32x4 oacc[4][4] = {};
  float lacc[4] = {0.f, 0.f, 0.f, 0.f};
  __syncthreads();  // all waves done reading U from Ts

  // pre-stage chunk 0 (t + VWo)
#pragma unroll
  for (int it = 0; it < 8; it++) {
    int f = it * 256 + tid;
    int row = f >> 5, cb = f & 31;
    gload16(T + (size_t)(k0 + row) * 256 + (size_t)((cb ^ (row & 7)) * 8),
            (char*)smem + (size_t)f * 16);
  }
#pragma unroll
  for (int it = 0; it < 8; it++) {
    int row = it * 32 + (tid >> 3);
    int cl = tid & 7, gc = cl ^ (row & 7);
    gload16(Wv + (size_t)row * NTOK + k0 + gc * 8,
            (char*)Ws + row * 128 + cl * 16);
  }
  __syncthreads();  // chunk 0 staged

  for (int kt = 0; kt < 18; kt++) {
    // S = U @ t^T : wave w owns q rows w*16..+15, all 64 keys
    f32x4 sacc[4] = {};
    __builtin_amdgcn_s_setprio(1);
#pragma unroll
    for (int ks = 0; ks < 8; ks++) {
#pragma unroll
      for (int kf = 0; kf < 4; kf++) {
        int key = kf * 16 + l15;
        bf16x8 tb_ = *(const bf16x8*)((char*)Ts + key * 512 +
                                      (((ks * 4 + h) ^ (key & 7)) * 16));
        sacc[kf] = MFMA16(ua[ks], tb_, sacc[kf]);
      }
    }
    __builtin_amdgcn_s_setprio(0);
    // P = exp(S) -> Ps (swizzled), l accumulate
#pragma unroll
    for (int kf = 0; kf < 4; kf++)
#pragma unroll
      for (int r = 0; r < 4; r++) {
        float pv = __expf(sacc[kf][r]);
        lacc[r] += pv;
        int q = w * 16 + h * 4 + r;
        int k = kf * 16 + l15;
        Ps[q * 64 + (((k >> 3) ^ (q & 7)) << 3) + (k & 7)] = f2bf(pv);
      }
    __syncthreads();  // B1: Ps visible; Ts free; drains Ws_{kt} stage
    // issue t-stage for next chunk (hides under PV; drained at B2)
    if (kt + 1 < 18) {
      const int kb = k0 + (kt + 1) * 64;
#pragma unroll
      for (int it = 0; it < 8; it++) {
        int f = it * 256 + tid;
        int row = f >> 5, cb = f & 31;
        gload16(T + (size_t)(kb + row) * 256 + (size_t)((cb ^ (row & 7)) * 8),
                (char*)smem + (size_t)f * 16);
      }
    }
    // O += P @ VWo : wave w owns c-slice w*64..+63, all 64 q
    __builtin_amdgcn_s_setprio(1);
#pragma unroll
    for (int ks2 = 0; ks2 < 2; ks2++) {
      bf16x8 pa[4];
#pragma unroll
      for (int m = 0; m < 4; m++) {
        int q = m * 16 + l15;
        pa[m] = *(const bf16x8*)((char*)Ps + q * 128 +
                                 (((ks2 * 4 + h) ^ (q & 7)) * 16));
      }
#pragma unroll
      for (int n = 0; n < 4; n++) {
        int c = w * 64 + n * 16 + l15;
        bf16x8 wb = *(const bf16x8*)((char*)Ws + c * 128 +
                                     (((ks2 * 4 + h) ^ (c & 7)) * 16));
#pragma unroll
        for (int m = 0; m < 4; m++) oacc[m][n] = MFMA16(pa[m], wb, oacc[m][n]);
      }
    }
    __builtin_amdgcn_s_setprio(0);
    __syncthreads();  // B2: PV done; Ws free; drains t_{kt+1} stage
    // issue Ws-stage for next chunk (hides under next S; drained at B1)
    if (kt + 1 < 18) {
      const int kb = k0 + (kt + 1) * 64;
#pragma unroll
      for (int it = 0; it < 8; it++) {
        int row = it * 32 + (tid >> 3);
        int cl = tid & 7, gc = cl ^ (row & 7);
        gload16(Wv + (size_t)row * NTOK + kb + gc * 8,
                (char*)Ws + row * 128 + cl * 16);
      }
    }
  }
  // l: reduce across the 16-lane groups, write per-row partials
#pragma unroll
  for (int r = 0; r < 4; r++) {
    float v = rsum16(lacc[r]);
    if (l15 == 0)
      l_part[(((size_t)bb * 2 + s) * 8 + z) * NTOK + q0 + w * 16 + h * 4 + r] =
          v;
  }
  // O epilogue: per-wave LDS transpose [64 c][72 q] bf16, coalesced store
  unsigned short* ldso = (unsigned short*)(smem + w * 9216);
#pragma unroll
  for (int m = 0; m < 4; m++)
#pragma unroll
    for (int n = 0; n < 4; n++)
#pragma unroll
      for (int r = 0; r < 4; r++)
        ldso[(n * 16 + l15) * 72 + m * 16 + h * 4 + r] = f2bf(oacc[m][n][r]);
  unsigned short* Out =
      Opart + ((((size_t)bb * 2 + s) * 8 + z) * 256 + w * 64) * NTOK + q0;
#pragma unroll
  for (int pp = 0; pp < 8; pp++) {
    int cc = pp * 8 + (lane >> 3);
    int qc = (lane & 7) * 8;
    *(bf16x8*)(Out + (size_t)cc * NTOK + qc) =
        *(const bf16x8*)(ldso + cc * 72 + qc);
  }
}

// ---------------------------------------------------------------------------
// reduce_out2: out[b][c][q] = bo[c] + sum_z [ (O0+O1)[b,z,c,q]/(l0+l1)[b,z,q]
//                                             + d[z][c] ].  grid (576, 4).
// Opart bf16 [b][s][z][c][q];  l_part f32 [b][s][z][q].
// ---------------------------------------------------------------------------
__global__ void reduce_out2(const unsigned short* __restrict__ Opart,
                            const float* __restrict__ l_part,
                            const float* __restrict__ dvec,
                            const float* __restrict__ bo,
                            float* __restrict__ out) {
  const int bb = blockIdx.y;
  int idx = (blockIdx.x * 256 + threadIdx.x) * 4;  // [0, 256*2304)
  int c = idx / NTOK;
  int q = idx - c * NTOK;
  const unsigned short* Ob = Opart + (size_t)bb * 2 * 8 * 256 * NTOK;
  const float* lb = l_part + (size_t)bb * 2 * 8 * NTOK;
  f32x4 acc = {bo[c], bo[c], bo[c], bo[c]};
#pragma unroll
  for (int z = 0; z < 8; z++) {
    ushort4v o0 = *(const ushort4v*)&Ob[((size_t)z * 256 + c) * NTOK + q];
    ushort4v o1 = *(const ushort4v*)&Ob[((size_t)(8 + z) * 256 + c) * NTOK + q];
    f32x4 l0 = *(const f32x4*)&lb[(size_t)z * NTOK + q];
    f32x4 l1 = *(const f32x4*)&lb[(size_t)(8 + z) * NTOK + q];
    float d = dvec[z * 256 + c];
#pragma unroll
    for (int j = 0; j < 4; j++)
      acc[j] += (bf2f(o0[j]) + bf2f(o1[j])) / (l0[j] + l1[j]) + d;
  }
  *(f32x4*)&out[(size_t)bb * CIN * NTOK + idx] = acc;
}

// ---------------------------------------------------------------------------
extern "C" void kernel_launch(void* const* d_in, const int* in_sizes, int n_in,
                              void* d_out, int out_size, void* d_ws,
                              size_t ws_size, hipStream_t stream) {
  const float* x = (const float*)d_in[0];
  const float* Wq = (const float*)d_in[1];
  const float* bq = (const float*)d_in[2];
  const float* Wk = (const float*)d_in[3];
  const float* bk = (const float*)d_in[4];
  const float* Wv = (const float*)d_in[5];
  const float* bv = (const float*)d_in[6];
  const float* Wo = (const float*)d_in[7];
  const float* bo = (const float*)d_in[8];
  float* out = (float*)d_out;
  (void)bk;  // bk terms are per-row softmax constants -> cancel exactly

  // ---- workspace layout (bf16 elements); total ~167 MB
  unsigned short* Wq_bf = (unsigned short*)d_ws;      // 256 x 4096
  unsigned short* Wk_bf = Wq_bf + 1048576;
  unsigned short* Wv_bf = Wk_bf + 1048576;
  unsigned short* WoT = Wv_bf + 1048576;              // 256 x 4096
  unsigned short* Hmat = WoT + 1048576;               // [8][256][256]
  unsigned short* MmatT = Hmat + 524288;              // [8][256][256]
  float* cvec = (float*)(MmatT + 524288);             // [8][256]
  float* dvec = cvec + 2048;                          // [8][256]
  unsigned short* tb = (unsigned short*)(dvec + 2048);  // [4][2304][256]
  unsigned short* Uc = tb + 4ull * 589824;            // [4][8][2304][256]
  unsigned short* VWoT = Uc + 32ull * 589824;         // [4][8][256][2304]
  unsigned short* Opart = VWoT + 32ull * 589824;      // [4][2][8][256][2304]
  float* l_part = (float*)(Opart + 64ull * 589824);   // [4][2][8][2304] f32
  size_t need_el = (size_t)((unsigned short*)(l_part + 4 * 2 * 8 * NTOK) -
                            (unsigned short*)d_ws);
  if (ws_size / 2 < need_el) return;

  dim3 tp(32, 8);
  conv_bf16<<<dim3(1024, 3), 256, 0, stream>>>(Wq, Wk, Wv, Wq_bf, Wk_bf,
                                               Wv_bf);
  transpose_to_bf16<<<dim3(72, 8, 4), tp, 0, stream>>>(
      x, tb, CIN, NTOK, (size_t)CIN * NTOK, (size_t)NTOK * CIN);
  transpose_to_bf16<<<dim3(8, 128, 1), tp, 0, stream>>>(Wo, WoT, DTOT, CIN, 0,
                                                        0);
  hgemm<<<dim3(2, 2, 8), 256, 0, stream>>>(Wk_bf, Wq_bf, Hmat);
  hgemm<<<dim3(2, 2, 8), 256, 0, stream>>>(WoT, Wv_bf, MmatT);
  cvec_kernel<<<dim3(8), 256, 0, stream>>>(Wk, bq, cvec);
  dvec_kernel<<<dim3(8), 256, 0, stream>>>(Wo, bv, dvec);

  proj2<<<dim3(18, 32, 4), 256, 0, stream>>>(tb, Hmat, cvec, MmatT, Uc, VWoT);
  fused_attn<<<dim3(2304), 256, 0, stream>>>(Uc, tb, VWoT, Opart, l_part);
  reduce_out2<<<dim3(576, 4), 256, 0, stream>>>(Opart, l_part, dvec, bo, out);
}